// Round 2
// baseline (26206.396 us; speedup 1.0000x reference)
//
#include <hip/hip_runtime.h>
#include <math.h>

// EncoderDecoderAttentionModel: B=64, T=256, H=D=256, L=3, NSTEPS=25, C=32000
#define TT    256
#define NB    64
#define HH    256
#define NSTEP 25
#define NCLS  32000
#define PADI  3

// ---------------- static device scratch (d_ws not used) ----------------
__device__ __align__(16) float g_hring[3][2][NB][HH];   // encoder h ping-pong (sc1 data)
__device__ __align__(16) float g_enchid[TT][NB][HH];    // masked top-layer hidden (cached)
__device__ __align__(16) float g_kp[NB][TT][HH];        // cached
__device__ __align__(16) float g_vp[NB][TT][HH];        // cached
__device__ __align__(16) float g_cfin[3][NB][HH];       // cached
__device__ __align__(16) float g_hdec[2][3][NB][HH];    // decoder h ping-pong (sc1 data)
__device__ __align__(16) float g_z0[NB][512];           // [embed ; ctx] (sc1 data)
__device__ float    g_wmax[256][NB];                    // per-WG argmax candidates (sc1)
__device__ int      g_wmaxi[256][NB];                   // (sc1)
__device__ int      g_len[NB];                          // cached (heavy barrier #1)
__device__ unsigned g_flags[256];                       // barrier flags (sc1)

__global__ void k_zero_flags(){ g_flags[threadIdx.x] = 0u; }

__device__ __forceinline__ float sigf(float v){ return 1.0f / (1.0f + expf(-v)); }

// ---- coherent (agent-scope, L1/L2-bypassing) accessors: no fences needed ----
#define SCOPE_AG __HIP_MEMORY_SCOPE_AGENT
__device__ __forceinline__ float ldc(const float* p){ return __hip_atomic_load(p, __ATOMIC_RELAXED, SCOPE_AG); }
__device__ __forceinline__ void  stc(float* p, float v){ __hip_atomic_store(p, v, __ATOMIC_RELAXED, SCOPE_AG); }
__device__ __forceinline__ int   ldi(const int* p){ return __hip_atomic_load(p, __ATOMIC_RELAXED, SCOPE_AG); }
__device__ __forceinline__ void  sti(int* p, int v){ __hip_atomic_store(p, v, __ATOMIC_RELAXED, SCOPE_AG); }
__device__ __forceinline__ unsigned ldu(const unsigned* p){ return __hip_atomic_load(p, __ATOMIC_RELAXED, SCOPE_AG); }
__device__ __forceinline__ void  stu(unsigned* p, unsigned v){ __hip_atomic_store(p, v, __ATOMIC_RELAXED, SCOPE_AG); }

#define DOT4(a_, x_, w_) (a_) += (x_).x*(w_).x + (x_).y*(w_).y + (x_).z*(w_).z + (x_).w*(w_).w

// LDS weight layout: [cb][gate][j][36]; j*36 % 32 == j*4 -> conflict-free b128.
#define WENC(cb,g,jj,u) (((((cb)*12+(g))*8+(jj))*36)+(u))

// ---- LIGHT grid barrier: no cache ops. All shared dynamic data travels sc1
// (already at LLC once vmcnt drains), so release = waitcnt + flag store. ----
__device__ __forceinline__ void gbar_light(int w, unsigned target){
  asm volatile("s_waitcnt vmcnt(0)" ::: "memory");   // each wave: sc1 stores at LLC
  __syncthreads();
  if (threadIdx.x == 0) stu(&g_flags[w], target);
  if (threadIdx.x < 64){
    const int i4 = threadIdx.x * 4;
    for (;;){
      unsigned a0 = ldu(&g_flags[i4+0]);
      unsigned a1 = ldu(&g_flags[i4+1]);
      unsigned a2 = ldu(&g_flags[i4+2]);
      unsigned a3 = ldu(&g_flags[i4+3]);
      if (__all((a0>=target) && (a1>=target) && (a2>=target) && (a3>=target))) break;
      __builtin_amdgcn_s_sleep(1);
    }
  }
  __syncthreads();
}

// ---- HEAVY grid barrier: full L2 writeback/invalidate (used 3x total) so
// normally-cached read-only phase outputs become visible chip-wide. ----
__device__ __forceinline__ void gbar_heavy(int w, unsigned target){
  asm volatile("s_waitcnt vmcnt(0)" ::: "memory");
  __syncthreads();
  __threadfence();                                   // release: wbl2 (per wave, per CU)
  __syncthreads();
  if (threadIdx.x == 0) stu(&g_flags[w], target);
  if (threadIdx.x < 64){
    const int i4 = threadIdx.x * 4;
    for (;;){
      unsigned a0 = ldu(&g_flags[i4+0]);
      unsigned a1 = ldu(&g_flags[i4+1]);
      unsigned a2 = ldu(&g_flags[i4+2]);
      unsigned a3 = ldu(&g_flags[i4+3]);
      if (__all((a0>=target) && (a1>=target) && (a2>=target) && (a3>=target))) break;
      __builtin_amdgcn_s_sleep(1);
    }
  }
  __syncthreads();
  __threadfence();                                   // acquire: inv stale L1/L2
  __syncthreads();
}

// load 32 consecutive floats (this lane's K-slice) coherently
__device__ __forceinline__ void ld32_sc1(const float* base, float* dst){
  #pragma unroll
  for (int u = 0; u < 32; ++u) dst[u] = ldc(base + u);
}
__device__ __forceinline__ void ld32_cached(const float* base, float* dst){
  const float4* p = (const float4*)base;
  #pragma unroll
  for (int u = 0; u < 8; ++u){
    float4 v = p[u];
    dst[4*u+0]=v.x; dst[4*u+1]=v.y; dst[4*u+2]=v.z; dst[4*u+3]=v.w;
  }
}

// decoder LSTM gate GEMM: 4 gate rows (h index = WG id), inputs read sc1.
template<int NCB, int BASE>
__device__ __forceinline__ void dec_gates(const float* sw, const float* i0, const float* i1,
                                          const float* i2, int j, float out4[4]){
  float xin[NCB*32];
  const float* ips[3] = { i0, i1, i2 };
  #pragma unroll
  for (int cb = 0; cb < NCB; ++cb)
    ld32_sc1(ips[cb] + j*32, &xin[cb*32]);
  float a0=0.f, a1=0.f, a2=0.f, a3=0.f;
  #pragma unroll
  for (int cb = 0; cb < NCB; ++cb){
    #pragma unroll
    for (int u = 0; u < 8; ++u){
      const float* xi = &xin[cb*32 + u*4];
      float4 w0 = *(const float4*)&sw[BASE + (((cb*4+0)*8+j)*36) + u*4];
      float4 w1 = *(const float4*)&sw[BASE + (((cb*4+1)*8+j)*36) + u*4];
      float4 w2 = *(const float4*)&sw[BASE + (((cb*4+2)*8+j)*36) + u*4];
      float4 w3 = *(const float4*)&sw[BASE + (((cb*4+3)*8+j)*36) + u*4];
      a0 += xi[0]*w0.x + xi[1]*w0.y + xi[2]*w0.z + xi[3]*w0.w;
      a1 += xi[0]*w1.x + xi[1]*w1.y + xi[2]*w1.z + xi[3]*w1.w;
      a2 += xi[0]*w2.x + xi[1]*w2.y + xi[2]*w2.z + xi[3]*w2.w;
      a3 += xi[0]*w3.x + xi[1]*w3.y + xi[2]*w3.z + xi[3]*w3.w;
    }
  }
  #pragma unroll
  for (int m = 1; m < 8; m <<= 1){
    a0 += __shfl_xor(a0, m); a1 += __shfl_xor(a1, m);
    a2 += __shfl_xor(a2, m); a3 += __shfl_xor(a3, m);
  }
  out4[0]=a0; out4[1]=a1; out4[2]=a2; out4[3]=a3;
}

__global__ void __launch_bounds__(512, 1)
k_main(const int*   __restrict__ p_x,
       const float* __restrict__ p_eemb,
       const float* __restrict__ p_eWih,  const float* __restrict__ p_eWhh,
       const float* __restrict__ p_ebih,  const float* __restrict__ p_ebhh,
       const float* __restrict__ p_Wq, const float* __restrict__ p_bq,
       const float* __restrict__ p_Wk, const float* __restrict__ p_bk,
       const float* __restrict__ p_Wv, const float* __restrict__ p_bv,
       const float* __restrict__ p_Wo, const float* __restrict__ p_bo,
       const float* __restrict__ p_demb,
       const float* __restrict__ p_dWih0, const float* __restrict__ p_dWihR,
       const float* __restrict__ p_dWhh,
       const float* __restrict__ p_dbih,  const float* __restrict__ p_dbhh,
       const float* __restrict__ p_dW,    const float* __restrict__ p_db,
       float* __restrict__ p_out)
{
  __shared__ __align__(16) float s_w[8064];     // enc: 6912 used; dec: 8064 used
  __shared__ __align__(16) float s_h2[64*260];  // stage-E h2 staging (pad 260)
  __shared__ float s_benc[12];
  __shared__ float s_bdec[12];
  __shared__ __align__(16) float s_hs[256];
  __shared__ __align__(16) float s_q[256];
  __shared__ __align__(16) float s_sc[256];
  __shared__ __align__(16) float s_at[256];
  __shared__ __align__(16) float s_ctx[256];
  __shared__ float s_rv[8];  __shared__ int s_ri[8];
  __shared__ float s_rv2[8][16]; __shared__ int s_ri2[8][16];

  const int w   = blockIdx.x;
  const int tid = threadIdx.x;
  const int b   = tid >> 3;      // batch lane (0..63)
  const int j   = tid & 7;       // K-split lane (0..7)
  unsigned bar  = 0;

  const int lay0 = (w < 255) ? (w / 85) : 0;
  const int h0   = (w < 255) ? ((w - lay0*85) * 3) : 0;

  // ---------------- init ----------------
  for (int fi = tid; fi < 6144; fi += 512){
    int g = fi >> 9, k = fi & 511;
    int e = g >> 2, gt = g & 3;
    int l   = (w < 255) ? lay0 : e;
    int hh2 = (w < 255) ? (h0 + e) : 255;
    int row = gt*256 + hh2;
    float v = (k < 256) ? p_eWih[((size_t)l*1024 + row)*256 + k]
                        : p_eWhh[((size_t)l*1024 + row)*256 + (k - 256)];
    s_w[WENC(k>>8, g, (k>>5)&7, k&31)] = v;
  }
  if (tid < 12){
    int e = tid >> 2, gt = tid & 3;
    int l   = (w < 255) ? lay0 : e;
    int hh2 = (w < 255) ? (h0 + e) : 255;
    int row = gt*256 + hh2;
    s_benc[tid] = p_ebih[l*1024 + row] + p_ebhh[l*1024 + row];
  }
  if (w < 64){
    int cnt = 0;
    if (tid < 256) cnt = (p_x[w*TT + tid] != PADI) ? 1 : 0;
    #pragma unroll
    for (int m = 1; m < 64; m <<= 1) cnt += __shfl_xor(cnt, m);
    if ((tid & 63) == 0) s_ri[tid >> 6] = cnt;
    __syncthreads();
    if (tid == 0){ int t2 = 0; for (int q2 = 0; q2 < 8; ++q2) t2 += s_ri[q2]; g_len[w] = t2; }
  }
  if (tid < 192){                       // zero initial-state slot (slot 1 == "t=-1")
    int fi = w*192 + tid;
    int l = fi >> 14, rem = fi & 16383;
    stc(&g_hring[l][1][rem >> 8][rem & 255], 0.f);
  }
  gbar_heavy(w, ++bar);                 // heavy #1: g_len + LDS settled

  const int len_b = g_len[b];

  // ---------------- encoder: layer-wavefront over diagonals ----------------
  float c_reg[3] = {0.f,0.f,0.f};
  float h_reg[3] = {0.f,0.f,0.f};

  for (int sdiag = 0; sdiag < TT + 2; ++sdiag){
    float acc[12];
    #pragma unroll
    for (int g = 0; g < 12; ++g) acc[g] = 0.f;

    if (w < 255){
      const int t = sdiag - lay0;
      if (t >= 0 && t < TT){
        float xv[32], hv[32];
        if (lay0 == 0) ld32_cached(p_eemb + (size_t)p_x[b*TT + t]*HH + j*32, xv);
        else           ld32_sc1(&g_hring[lay0-1][t & 1][b][0] + j*32, xv);
        ld32_sc1(&g_hring[lay0][(t & 1) ^ 1][b][0] + j*32, hv);
        #pragma unroll
        for (int u = 0; u < 8; ++u){
          const float* xi = &xv[u*4];
          const float* hi = &hv[u*4];
          #pragma unroll
          for (int g = 0; g < 12; ++g){
            float4 wx = *(const float4*)&s_w[WENC(0, g, j, u*4)];
            float4 wh = *(const float4*)&s_w[WENC(1, g, j, u*4)];
            acc[g] += xi[0]*wx.x + xi[1]*wx.y + xi[2]*wx.z + xi[3]*wx.w
                    + hi[0]*wh.x + hi[1]*wh.y + hi[2]*wh.z + hi[3]*wh.w;
          }
        }
      }
    } else {
      #pragma unroll
      for (int e = 0; e < 3; ++e){
        const int t = sdiag - e;
        if (t >= 0 && t < TT){
          float xv[32], hv[32];
          if (e == 0) ld32_cached(p_eemb + (size_t)p_x[b*TT + t]*HH + j*32, xv);
          else        ld32_sc1(&g_hring[e-1][t & 1][b][0] + j*32, xv);
          ld32_sc1(&g_hring[e][(t & 1) ^ 1][b][0] + j*32, hv);
          #pragma unroll
          for (int u = 0; u < 8; ++u){
            const float* xi = &xv[u*4];
            const float* hi = &hv[u*4];
            #pragma unroll
            for (int g2 = 0; g2 < 4; ++g2){
              float4 wx = *(const float4*)&s_w[WENC(0, e*4+g2, j, u*4)];
              float4 wh = *(const float4*)&s_w[WENC(1, e*4+g2, j, u*4)];
              acc[e*4+g2] += xi[0]*wx.x + xi[1]*wx.y + xi[2]*wx.z + xi[3]*wx.w
                           + hi[0]*wh.x + hi[1]*wh.y + hi[2]*wh.z + hi[3]*wh.w;
            }
          }
        }
      }
    }

    #pragma unroll
    for (int g = 0; g < 12; ++g){
      float v = acc[g];
      v += __shfl_xor(v, 1); v += __shfl_xor(v, 2); v += __shfl_xor(v, 4);
      acc[g] = v;
    }

    if (j == 0){
      #pragma unroll
      for (int e = 0; e < 3; ++e){
        const int lay = (w < 255) ? lay0 : e;
        const int hh2 = (w < 255) ? (h0 + e) : 255;
        const int t = sdiag - lay;
        if (t >= 0 && t < TT){
          float iv = acc[e*4+0] + s_benc[e*4+0];
          float fv = acc[e*4+1] + s_benc[e*4+1];
          float gv = acc[e*4+2] + s_benc[e*4+2];
          float ov = acc[e*4+3] + s_benc[e*4+3];
          float c2 = sigf(fv)*c_reg[e] + sigf(iv)*tanhf(gv);
          float h2 = sigf(ov)*tanhf(c2);
          bool valid = (t < len_b);
          if (valid){ c_reg[e] = c2; h_reg[e] = h2; }    // freeze past length
          stc(&g_hring[lay][t & 1][b][hh2], h_reg[e]);
          if (lay == 2) g_enchid[t][b][hh2] = valid ? h_reg[e] : 0.f;  // cached
        }
      }
    }
    gbar_light(w, ++bar);
  }

  if (j == 0){
    #pragma unroll
    for (int e = 0; e < 3; ++e){
      const int lay = (w < 255) ? lay0 : e;
      const int hh2 = (w < 255) ? (h0 + e) : 255;
      g_cfin[lay][b][hh2] = c_reg[e];               // cached
    }
  }
  gbar_heavy(w, ++bar);                              // heavy #2: enchid + cfin visible

  // ---------------- K/V projections (cached I/O; flushed by heavy #3) ----------------
  {
    const int b2 = w >> 2, t0 = (w & 3) * 64;
    const int n1 = tid & 127, rq = tid >> 7;
    for (int p = 0; p < 4; ++p){
      const int n = p*128 + n1;
      const float* wrow = (n < 256) ? (p_Wk + (size_t)n*HH) : (p_Wv + (size_t)(n-256)*HH);
      const float bias  = (n < 256) ? p_bk[n] : p_bv[n-256];
      const float4* wr4 = (const float4*)wrow;
      const float* hb = &g_enchid[t0 + rq*16][b2][0];
      const float4* hr[16];
      #pragma unroll
      for (int r = 0; r < 16; ++r) hr[r] = (const float4*)(hb + (size_t)r*NB*HH);
      float a16[16];
      #pragma unroll
      for (int r = 0; r < 16; ++r) a16[r] = 0.f;
      for (int k4 = 0; k4 < 64; ++k4){
        float4 wv = wr4[k4];
        #pragma unroll
        for (int r = 0; r < 16; ++r){ float4 h4 = hr[r][k4]; DOT4(a16[r], h4, wv); }
      }
      float* orow = (n < 256) ? &g_kp[b2][t0 + rq*16][n] : &g_vp[b2][t0 + rq*16][n-256];
      #pragma unroll
      for (int r = 0; r < 16; ++r) orow[(size_t)r*HH] = a16[r] + bias;
    }
  }

  // decoder weights for h=w (all 3 layers) -> LDS
  for (int fi = tid; fi < 3072; fi += 512){
    int g = fi / 768, k = fi % 768; int row = g*256 + w;
    float v = (k < 512) ? p_dWih0[(size_t)row*512 + k]
                        : p_dWhh[(size_t)row*HH + (k - 512)];
    s_w[(((k>>8)*4 + g)*8 + ((k>>5)&7))*36 + (k&31)] = v;
  }
  for (int fi = tid; fi < 2048; fi += 512){
    int g = fi / 512, k = fi % 512; int row = g*256 + w;
    float v = (k < 256) ? p_dWihR[(size_t)row*HH + k]
                        : p_dWhh[(size_t)(1024 + row)*HH + (k - 256)];
    s_w[3456 + (((k>>8)*4 + g)*8 + ((k>>5)&7))*36 + (k&31)] = v;
  }
  for (int fi = tid; fi < 2048; fi += 512){
    int g = fi / 512, k = fi % 512; int row = g*256 + w;
    float v = (k < 256) ? p_dWihR[(size_t)(1024 + row)*HH + k]
                        : p_dWhh[(size_t)(2048 + row)*HH + (k - 256)];
    s_w[5760 + (((k>>8)*4 + g)*8 + ((k>>5)&7))*36 + (k&31)] = v;
  }
  if (tid < 12){
    int l = tid >> 2, g = tid & 3; int row = g*256 + w;
    s_bdec[tid] = p_dbih[l*1024 + row] + p_dbhh[l*1024 + row];
  }
  gbar_heavy(w, ++bar);                              // heavy #3: kp/vp visible

  // ---------------- decoder init (sc1 data) ----------------
  if (tid < 192){
    int fi = w*192 + tid;
    int l = fi >> 14, rem = fi & 16383;
    stc(&g_hdec[0][l][rem >> 8][rem & 255], ldc(&g_hring[l][1][rem >> 8][rem & 255]));
  }
  float c_d0 = 0.f, c_d1 = 0.f, c_d2 = 0.f;
  if (j == 0){
    c_d0 = g_cfin[0][b][w]; c_d1 = g_cfin[1][b][w]; c_d2 = g_cfin[2][b][w];
  }
  gbar_light(w, ++bar);

  // ---------------- decoder steps ----------------
  for (int st = 0; st < NSTEP; ++st){
    const int slot = st & 1, nxt = slot ^ 1;

    // ---- stage A: argmax-reduce, embed, attention, z0 (WGs 0..63) ----
    if (w < 64){
      const int bA = w;
      int tok = 0;                                  // SOS
      if (st > 0){
        float v = -1e38f; int idx = 0;
        if (tid < 256){ v = ldc(&g_wmax[tid][bA]); idx = ldi(&g_wmaxi[tid][bA]); }
        #pragma unroll
        for (int m = 1; m < 64; m <<= 1){
          float ov = __shfl_xor(v, m); int oi = __shfl_xor(idx, m);
          if (ov > v || (ov == v && oi < idx)){ v = ov; idx = oi; }
        }
        if ((tid & 63) == 0){ s_rv[tid >> 6] = v; s_ri[tid >> 6] = idx; }
        __syncthreads();
        if (tid == 0){
          float bv2 = s_rv[0]; int bi2 = s_ri[0];
          for (int q2 = 1; q2 < 8; ++q2){
            float ov = s_rv[q2]; int oi = s_ri[q2];
            if (ov > bv2 || (ov == bv2 && oi < bi2)){ bv2 = ov; bi2 = oi; }
          }
          s_ri[0] = bi2;
        }
        __syncthreads();
        tok = s_ri[0];
      }
      if (tid < 256)
        s_hs[tid] = ldc(&g_hdec[slot][0][bA][tid]) + ldc(&g_hdec[slot][1][bA][tid])
                  + ldc(&g_hdec[slot][2][bA][tid]);
      __syncthreads();
      if (tid < 256){                                // q = hsum @ Wq.T + bq
        float a = p_bq[tid];
        const float4* wr = (const float4*)(p_Wq + (size_t)tid*HH);
        #pragma unroll 8
        for (int k4 = 0; k4 < 64; ++k4){
          float4 wv = wr[k4]; float4 h4 = *(const float4*)&s_hs[k4*4]; DOT4(a, h4, wv);
        }
        s_q[tid] = a;
      }
      __syncthreads();
      if (tid < 256){                                // scores
        float a = 0.f;
        const float4* kr = (const float4*)&g_kp[bA][tid][0];
        #pragma unroll 8
        for (int k4 = 0; k4 < 64; ++k4){
          float4 kv = kr[k4]; float4 q4 = *(const float4*)&s_q[k4*4]; DOT4(a, q4, kv);
        }
        s_sc[tid] = a * 0.0625f;                     // 1/sqrt(256)
      }
      __syncthreads();
      {                                              // softmax
        float sv = (tid < 256) ? s_sc[tid] : -1e38f;
        float m2 = sv;
        #pragma unroll
        for (int m = 1; m < 64; m <<= 1) m2 = fmaxf(m2, __shfl_xor(m2, m));
        if ((tid & 63) == 0) s_rv[tid >> 6] = m2;
        __syncthreads();
        if (tid == 0){ float mm = s_rv[0]; for (int q2 = 1; q2 < 8; ++q2) mm = fmaxf(mm, s_rv[q2]); s_rv[0] = mm; }
        __syncthreads();
        const float mx = s_rv[0];
        float ev = (tid < 256) ? expf(sv - mx) : 0.f;
        float ss = ev;
        #pragma unroll
        for (int m = 1; m < 64; m <<= 1) ss += __shfl_xor(ss, m);
        __syncthreads();
        if ((tid & 63) == 0) s_rv[tid >> 6] = ss;
        __syncthreads();
        if (tid == 0){ float t2 = 0.f; for (int q2 = 0; q2 < 8; ++q2) t2 += s_rv[q2]; s_rv[0] = t2; }
        __syncthreads();
        if (tid < 256) s_at[tid] = ev / s_rv[0];
      }
      __syncthreads();
      if (tid < 256){                                // ctx = attn @ vp
        float a = 0.f;
        const float* vb = &g_vp[bA][0][tid];
        #pragma unroll 4
        for (int t4 = 0; t4 < 64; ++t4){
          float4 a4 = *(const float4*)&s_at[t4*4];
          a += a4.x*vb[(size_t)(t4*4+0)*HH] + a4.y*vb[(size_t)(t4*4+1)*HH]
             + a4.z*vb[(size_t)(t4*4+2)*HH] + a4.w*vb[(size_t)(t4*4+3)*HH];
        }
        s_ctx[tid] = a;
      }
      __syncthreads();
      if (tid < 256){                                // ctx @ Wo.T + bo ; z0
        float a = p_bo[tid];
        const float4* wr = (const float4*)(p_Wo + (size_t)tid*HH);
        #pragma unroll 8
        for (int k4 = 0; k4 < 64; ++k4){
          float4 wv = wr[k4]; float4 c4 = *(const float4*)&s_ctx[k4*4]; DOT4(a, c4, wv);
        }
        stc(&g_z0[bA][256 + tid], a);
        stc(&g_z0[bA][tid], p_demb[(size_t)tok*HH + tid]);
      }
    }
    gbar_light(w, ++bar);

    // ---- stages B/C/D: 3 LSTM layers, h=w per WG ----
    {
      float g4[4];
      dec_gates<3, 0>(s_w, &g_z0[b][0], &g_z0[b][256], &g_hdec[slot][0][b][0], j, g4);
      if (j == 0){
        float iv = g4[0]+s_bdec[0], fv = g4[1]+s_bdec[1], gv = g4[2]+s_bdec[2], ov = g4[3]+s_bdec[3];
        float c2 = sigf(fv)*c_d0 + sigf(iv)*tanhf(gv); c_d0 = c2;
        stc(&g_hdec[nxt][0][b][w], sigf(ov)*tanhf(c2));
      }
    }
    gbar_light(w, ++bar);
    {
      float g4[4];
      dec_gates<2, 3456>(s_w, &g_hdec[nxt][0][b][0], &g_hdec[slot][1][b][0], nullptr, j, g4);
      if (j == 0){
        float iv = g4[0]+s_bdec[4], fv = g4[1]+s_bdec[5], gv = g4[2]+s_bdec[6], ov = g4[3]+s_bdec[7];
        float c2 = sigf(fv)*c_d1 + sigf(iv)*tanhf(gv); c_d1 = c2;
        stc(&g_hdec[nxt][1][b][w], sigf(ov)*tanhf(c2));
      }
    }
    gbar_light(w, ++bar);
    {
      float g4[4];
      dec_gates<2, 5760>(s_w, &g_hdec[nxt][1][b][0], &g_hdec[slot][2][b][0], nullptr, j, g4);
      if (j == 0){
        float iv = g4[0]+s_bdec[8], fv = g4[1]+s_bdec[9], gv = g4[2]+s_bdec[10], ov = g4[3]+s_bdec[11];
        float c2 = sigf(fv)*c_d2 + sigf(iv)*tanhf(gv); c_d2 = c2;
        stc(&g_hdec[nxt][2][b][w], sigf(ov)*tanhf(c2));
      }
    }
    gbar_light(w, ++bar);

    // ---- stage E: logits GEMM (125 classes/WG) + partial argmax ----
    {
      // stage h2 (64x256) into LDS via coherent loads: 32 floats/thread
      {
        const int bb = tid >> 3, part = tid & 7;
        const float* src = &g_hdec[nxt][2][bb][part*32];
        float tmp[32];
        #pragma unroll
        for (int u = 0; u < 32; ++u) tmp[u] = ldc(src + u);
        float* dst = &s_h2[bb*260 + part*32];
        #pragma unroll
        for (int u = 0; u < 8; ++u){
          *(float4*)(dst + u*4) = make_float4(tmp[4*u], tmp[4*u+1], tmp[4*u+2], tmp[4*u+3]);
        }
      }
      __syncthreads();

      const int cq = tid & 127, qb = tid >> 7;
      const bool cok = (cq < 125);
      const int c  = w*125 + cq;
      const int cc = cok ? c : (w*125);
      const float4* wr = (const float4*)(p_dW + (size_t)cc*HH);
      const float4* zr[16];
      #pragma unroll
      for (int r = 0; r < 16; ++r) zr[r] = (const float4*)&s_h2[(qb*16 + r)*260];
      float a16[16];
      #pragma unroll
      for (int r = 0; r < 16; ++r) a16[r] = 0.f;
      for (int k4 = 0; k4 < 64; ++k4){
        float4 wv = wr[k4];
        #pragma unroll
        for (int r = 0; r < 16; ++r){ float4 z4 = zr[r][k4]; DOT4(a16[r], z4, wv); }
      }
      const float bias = cok ? p_db[cc] : 0.f;
      #pragma unroll
      for (int r = 0; r < 16; ++r){
        const int bb = qb*16 + r;
        float val = a16[r] + bias;
        if (cok) p_out[((size_t)bb*NSTEP + st)*NCLS + c] = val;
        float v = cok ? val : -1e38f;
        int idx = cok ? c : 0x7fffffff;
        #pragma unroll
        for (int m = 1; m < 64; m <<= 1){
          float ov = __shfl_xor(v, m); int oi = __shfl_xor(idx, m);
          if (ov > v || (ov == v && oi < idx)){ v = ov; idx = oi; }
        }
        if ((tid & 63) == 0){ s_rv2[tid >> 6][r] = v; s_ri2[tid >> 6][r] = idx; }
      }
      __syncthreads();
      if (tid < 64){
        const int qb2 = tid >> 4, r = tid & 15;
        float v1 = s_rv2[qb2*2][r];   int i1 = s_ri2[qb2*2][r];
        float v2 = s_rv2[qb2*2+1][r]; int i2 = s_ri2[qb2*2+1][r];
        bool take2 = (v2 > v1) || (v2 == v1 && i2 < i1);
        stc(&g_wmax[w][qb2*16 + r],  take2 ? v2 : v1);
        sti(&g_wmaxi[w][qb2*16 + r], take2 ? i2 : i1);
      }
      __syncthreads();
    }
    gbar_light(w, ++bar);
  }
}

extern "C" void kernel_launch(void* const* d_in, const int* in_sizes, int n_in,
                              void* d_out, int out_size, void* d_ws, size_t ws_size,
                              hipStream_t stream){
  (void)in_sizes; (void)n_in; (void)out_size; (void)d_ws; (void)ws_size;
  const int*   x     = (const int*)d_in[0];
  const float* eemb  = (const float*)d_in[2];
  const float* eWih  = (const float*)d_in[3];
  const float* eWhh  = (const float*)d_in[4];
  const float* ebih  = (const float*)d_in[5];
  const float* ebhh  = (const float*)d_in[6];
  const float* Wq    = (const float*)d_in[7];
  const float* bq    = (const float*)d_in[8];
  const float* Wk    = (const float*)d_in[9];
  const float* bk    = (const float*)d_in[10];
  const float* Wv    = (const float*)d_in[11];
  const float* bv    = (const float*)d_in[12];
  const float* Wo    = (const float*)d_in[13];
  const float* bo    = (const float*)d_in[14];
  const float* demb  = (const float*)d_in[15];
  const float* dWih0 = (const float*)d_in[16];
  const float* dWihR = (const float*)d_in[17];
  const float* dWhh  = (const float*)d_in[18];
  const float* dbih  = (const float*)d_in[19];
  const float* dbhh  = (const float*)d_in[20];
  const float* dW    = (const float*)d_in[21];
  const float* db    = (const float*)d_in[22];
  float* out = (float*)d_out;

  k_zero_flags<<<dim3(1), dim3(256), 0, stream>>>();
  k_main<<<dim3(256), dim3(512), 0, stream>>>(
      x, eemb, eWih, eWhh, ebih, ebhh,
      Wq, bq, Wk, bk, Wv, bv, Wo, bo,
      demb, dWih0, dWihR, dWhh, dbih, dbhh, dW, db, out);
}

// Round 3
// 6890.807 us; speedup vs baseline: 3.8031x; 3.8031x over previous
//
#include <hip/hip_runtime.h>
#include <math.h>

// EncoderDecoderAttentionModel: B=64, T=256, H=D=256, L=3, NSTEPS=25, C=32000
#define TT    256
#define NB    64
#define HH    256
#define NSTEP 25
#define NCLS  32000
#define PADI  3

// ---------------- static device scratch ----------------
__device__ __align__(16) float g_hring[3][2][NB][HH];   // encoder h ping-pong (coherent)
__device__ __align__(16) float g_enchid[TT][NB][HH];    // write-once (sc1 store, cached read)
__device__ __align__(16) float g_kp[NB][TT][HH];        // write-once
__device__ __align__(16) float g_vp[NB][TT][HH];        // write-once
__device__ __align__(16) float g_cfin[3][NB][HH];       // write-once
__device__ __align__(16) float g_hdec[2][3][NB][HH];    // decoder h ping-pong (coherent)
__device__ __align__(16) float g_z0[NB][512];           // [embed ; ctx] (coherent)
__device__ float    g_wmax[256][NB];                    // argmax candidates (coherent)
__device__ int      g_wmaxi[256][NB];
__device__ int      g_len[NB];
__device__ unsigned g_flags[256];                       // barrier flags

__global__ void k_zero_flags(){ g_flags[threadIdx.x] = 0u; }

__device__ __forceinline__ float sigf(float v){ return 1.0f / (1.0f + expf(-v)); }

// ---- coherent accessors (agent scope, relaxed): visible chip-wide w/o fences ----
#define SCOPE_AG __HIP_MEMORY_SCOPE_AGENT
typedef unsigned long long u64;
__device__ __forceinline__ float2 ld2(const float* p){
  u64 v = __hip_atomic_load((const u64*)p, __ATOMIC_RELAXED, SCOPE_AG);
  float2 r; __builtin_memcpy(&r, &v, 8); return r;
}
__device__ __forceinline__ void st2(float* p, float2 f){
  u64 v; __builtin_memcpy(&v, &f, 8);
  __hip_atomic_store((u64*)p, v, __ATOMIC_RELAXED, SCOPE_AG);
}
__device__ __forceinline__ float ldc(const float* p){ return __hip_atomic_load(p, __ATOMIC_RELAXED, SCOPE_AG); }
__device__ __forceinline__ void  stc(float* p, float v){ __hip_atomic_store(p, v, __ATOMIC_RELAXED, SCOPE_AG); }
__device__ __forceinline__ int   ldi(const int* p){ return __hip_atomic_load(p, __ATOMIC_RELAXED, SCOPE_AG); }
__device__ __forceinline__ void  sti(int* p, int v){ __hip_atomic_store(p, v, __ATOMIC_RELAXED, SCOPE_AG); }
__device__ __forceinline__ unsigned ldu(const unsigned* p){ return __hip_atomic_load(p, __ATOMIC_RELAXED, SCOPE_AG); }
__device__ __forceinline__ void  stu(unsigned* p, unsigned v){ __hip_atomic_store(p, v, __ATOMIC_RELAXED, SCOPE_AG); }

#define DOT4(a_, x_, w_) (a_) += (x_).x*(w_).x + (x_).y*(w_).y + (x_).z*(w_).z + (x_).w*(w_).w

// LDS weight layout: [cb][gate][j][36] with K-permutation k = 16u + 2j + c
// (j*36 % 32 == j*4 -> the 8 j-groups hit disjoint bank quads, broadcast across b-lanes)
#define WENC(cb,g,jj,u) (((((cb)*12+(g))*8+(jj))*36)+(u))

// ---- light grid barrier: drain vmem (coherent stores at LLC), flag, poll ----
__device__ __forceinline__ void gbar(int w, unsigned target){
  asm volatile("s_waitcnt vmcnt(0)" ::: "memory");
  __syncthreads();
  if (threadIdx.x == 0) stu(&g_flags[w], target);
  if (threadIdx.x < 64){
    const int i4 = threadIdx.x * 4;
    for (;;){
      unsigned a0 = ldu(&g_flags[i4+0]);
      unsigned a1 = ldu(&g_flags[i4+1]);
      unsigned a2 = ldu(&g_flags[i4+2]);
      unsigned a3 = ldu(&g_flags[i4+3]);
      if (__all((a0>=target) && (a1>=target) && (a2>=target) && (a3>=target))) break;
      __builtin_amdgcn_s_sleep(1);
    }
  }
  __syncthreads();
}

// decoder LSTM gate GEMM: 4 gate rows (h index = WG id), inputs coherent+coalesced.
template<int NCB, int BASE>
__device__ __forceinline__ void dec_gates(const float* sw, const float* i0, const float* i1,
                                          const float* i2, int j, float out4[4]){
  float a0=0.f, a1=0.f, a2=0.f, a3=0.f;
  const float* ips[3] = { i0, i1, i2 };
  #pragma unroll
  for (int cb = 0; cb < NCB; ++cb){
    float2 xin[16];
    #pragma unroll
    for (int u = 0; u < 16; ++u) xin[u] = ld2(ips[cb] + u*16 + 2*j);
    #pragma unroll
    for (int u2 = 0; u2 < 8; ++u2){
      float2 pa = xin[2*u2], pb = xin[2*u2+1];
      const float* wb = &sw[BASE + (((cb*4+0)*8+j)*36) + u2*4];
      float4 w0 = *(const float4*)(wb);
      float4 w1 = *(const float4*)(wb + 288);
      float4 w2 = *(const float4*)(wb + 576);
      float4 w3 = *(const float4*)(wb + 864);
      a0 += pa.x*w0.x + pa.y*w0.y + pb.x*w0.z + pb.y*w0.w;
      a1 += pa.x*w1.x + pa.y*w1.y + pb.x*w1.z + pb.y*w1.w;
      a2 += pa.x*w2.x + pa.y*w2.y + pb.x*w2.z + pb.y*w2.w;
      a3 += pa.x*w3.x + pa.y*w3.y + pb.x*w3.z + pb.y*w3.w;
    }
  }
  #pragma unroll
  for (int m = 1; m < 8; m <<= 1){
    a0 += __shfl_xor(a0, m); a1 += __shfl_xor(a1, m);
    a2 += __shfl_xor(a2, m); a3 += __shfl_xor(a3, m);
  }
  out4[0]=a0; out4[1]=a1; out4[2]=a2; out4[3]=a3;
}

__global__ void __launch_bounds__(512, 1)
k_main(const int*   __restrict__ p_x,
       const float* __restrict__ p_eemb,
       const float* __restrict__ p_eWih,  const float* __restrict__ p_eWhh,
       const float* __restrict__ p_ebih,  const float* __restrict__ p_ebhh,
       const float* __restrict__ p_Wq, const float* __restrict__ p_bq,
       const float* __restrict__ p_Wk, const float* __restrict__ p_bk,
       const float* __restrict__ p_Wv, const float* __restrict__ p_bv,
       const float* __restrict__ p_Wo, const float* __restrict__ p_bo,
       const float* __restrict__ p_demb,
       const float* __restrict__ p_dWih0, const float* __restrict__ p_dWihR,
       const float* __restrict__ p_dWhh,
       const float* __restrict__ p_dbih,  const float* __restrict__ p_dbhh,
       const float* __restrict__ p_dW,    const float* __restrict__ p_db,
       float* __restrict__ p_out)
{
  __shared__ __align__(16) float s_w[8064];       // enc: 6912 used; dec: 8064 used
  __shared__ __align__(16) float s_h2[NB*HH];     // stage-E h2 staging, flat [64][256]
  __shared__ float s_benc[12];
  __shared__ float s_bdec[12];
  __shared__ __align__(16) float s_hs[256];
  __shared__ __align__(16) float s_q[256];
  __shared__ __align__(16) float s_sc[256];
  __shared__ __align__(16) float s_at[256];
  __shared__ __align__(16) float s_ctx[256];
  __shared__ float s_rv[8];  __shared__ int s_ri[8];
  __shared__ float s_rv2[8][16]; __shared__ int s_ri2[8][16];

  const int w   = blockIdx.x;
  const int tid = threadIdx.x;
  const int b   = tid >> 3;      // batch lane (0..63)
  const int j   = tid & 7;       // K-split lane (0..7); owns k = {16u + 2j + c}
  unsigned bar  = 0;

  const int lay0 = (w < 255) ? (w / 85) : 0;
  const int h0   = (w < 255) ? ((w - lay0*85) * 3) : 0;

  // ---------------- init: lengths, encoder weights -> LDS (permuted), zero ring ----
  for (int fi = tid; fi < 6144; fi += 512){
    int g = fi >> 9, k = fi & 511;
    int e = g >> 2, gt = g & 3;
    int l   = (w < 255) ? lay0 : e;
    int hh2 = (w < 255) ? (h0 + e) : 255;
    int row = gt*256 + hh2;
    float v = (k < 256) ? p_eWih[((size_t)l*1024 + row)*256 + k]
                        : p_eWhh[((size_t)l*1024 + row)*256 + (k - 256)];
    int cb = k >> 8, kk = k & 255;
    s_w[WENC(cb, g, (kk & 15) >> 1, ((kk >> 4) << 1) | (kk & 1))] = v;
  }
  if (tid < 12){
    int e = tid >> 2, gt = tid & 3;
    int l   = (w < 255) ? lay0 : e;
    int hh2 = (w < 255) ? (h0 + e) : 255;
    int row = gt*256 + hh2;
    s_benc[tid] = p_ebih[l*1024 + row] + p_ebhh[l*1024 + row];
  }
  if (w < 64){
    int cnt = 0;
    if (tid < 256) cnt = (p_x[w*TT + tid] != PADI) ? 1 : 0;
    #pragma unroll
    for (int m = 1; m < 64; m <<= 1) cnt += __shfl_xor(cnt, m);
    if ((tid & 63) == 0) s_ri[tid >> 6] = cnt;
    __syncthreads();
    if (tid == 0){ int t2 = 0; for (int q2 = 0; q2 < 8; ++q2) t2 += s_ri[q2]; sti(&g_len[w], t2); }
  }
  if (tid < 192){                       // zero initial-state slot (slot 1 == "t=-1")
    int fi = w*192 + tid;
    int l = fi >> 14, rem = fi & 16383;
    stc(&g_hring[l][1][rem >> 8][rem & 255], 0.f);
  }
  gbar(w, ++bar);

  const int len_b = ldi(&g_len[b]);

  // ---------------- encoder: layer-wavefront over diagonals ----------------
  float c_reg[3] = {0.f,0.f,0.f};
  float h_reg[3] = {0.f,0.f,0.f};

  for (int sdiag = 0; sdiag < TT + 2; ++sdiag){
    float acc[12];
    #pragma unroll
    for (int g = 0; g < 12; ++g) acc[g] = 0.f;

    if (w < 255){
      const int t = sdiag - lay0;
      if (t >= 0 && t < TT){
        float2 x2[16], h2[16];
        if (lay0 == 0){
          const float* xs = p_eemb + (size_t)p_x[b*TT + t]*HH;
          #pragma unroll
          for (int u = 0; u < 16; ++u) x2[u] = *(const float2*)(xs + u*16 + 2*j);
        } else {
          const float* xs = &g_hring[lay0-1][t & 1][b][0];
          #pragma unroll
          for (int u = 0; u < 16; ++u) x2[u] = ld2(xs + u*16 + 2*j);
        }
        {
          const float* hsv = &g_hring[lay0][(t & 1) ^ 1][b][0];
          #pragma unroll
          for (int u = 0; u < 16; ++u) h2[u] = ld2(hsv + u*16 + 2*j);
        }
        #pragma unroll
        for (int u2 = 0; u2 < 8; ++u2){
          float2 xa = x2[2*u2], xb = x2[2*u2+1];
          float2 ha = h2[2*u2], hb = h2[2*u2+1];
          #pragma unroll
          for (int g = 0; g < 12; ++g){
            float4 wx = *(const float4*)&s_w[WENC(0, g, j, u2*4)];
            float4 wh = *(const float4*)&s_w[WENC(1, g, j, u2*4)];
            acc[g] += xa.x*wx.x + xa.y*wx.y + xb.x*wx.z + xb.y*wx.w
                    + ha.x*wh.x + ha.y*wh.y + hb.x*wh.z + hb.y*wh.w;
          }
        }
      }
    } else {
      #pragma unroll
      for (int e = 0; e < 3; ++e){
        const int t = sdiag - e;
        if (t >= 0 && t < TT){
          float2 x2[16], h2[16];
          if (e == 0){
            const float* xs = p_eemb + (size_t)p_x[b*TT + t]*HH;
            #pragma unroll
            for (int u = 0; u < 16; ++u) x2[u] = *(const float2*)(xs + u*16 + 2*j);
          } else {
            const float* xs = &g_hring[e-1][t & 1][b][0];
            #pragma unroll
            for (int u = 0; u < 16; ++u) x2[u] = ld2(xs + u*16 + 2*j);
          }
          {
            const float* hsv = &g_hring[e][(t & 1) ^ 1][b][0];
            #pragma unroll
            for (int u = 0; u < 16; ++u) h2[u] = ld2(hsv + u*16 + 2*j);
          }
          #pragma unroll
          for (int u2 = 0; u2 < 8; ++u2){
            float2 xa = x2[2*u2], xb = x2[2*u2+1];
            float2 ha = h2[2*u2], hb = h2[2*u2+1];
            #pragma unroll
            for (int g2 = 0; g2 < 4; ++g2){
              float4 wx = *(const float4*)&s_w[WENC(0, e*4+g2, j, u2*4)];
              float4 wh = *(const float4*)&s_w[WENC(1, e*4+g2, j, u2*4)];
              acc[e*4+g2] += xa.x*wx.x + xa.y*wx.y + xb.x*wx.z + xb.y*wx.w
                           + ha.x*wh.x + ha.y*wh.y + hb.x*wh.z + hb.y*wh.w;
            }
          }
        }
      }
    }

    #pragma unroll
    for (int g = 0; g < 12; ++g){
      float v = acc[g];
      v += __shfl_xor(v, 1); v += __shfl_xor(v, 2); v += __shfl_xor(v, 4);
      acc[g] = v;
    }

    if (j == 0){
      #pragma unroll
      for (int e = 0; e < 3; ++e){
        const int lay = (w < 255) ? lay0 : e;
        const int hh2 = (w < 255) ? (h0 + e) : 255;
        const int t = sdiag - lay;
        if (t >= 0 && t < TT){
          float iv = acc[e*4+0] + s_benc[e*4+0];
          float fv = acc[e*4+1] + s_benc[e*4+1];
          float gv = acc[e*4+2] + s_benc[e*4+2];
          float ov = acc[e*4+3] + s_benc[e*4+3];
          float c2 = sigf(fv)*c_reg[e] + sigf(iv)*tanhf(gv);
          float h2v = sigf(ov)*tanhf(c2);
          bool valid = (t < len_b);
          if (valid){ c_reg[e] = c2; h_reg[e] = h2v; }   // freeze past length
          stc(&g_hring[lay][t & 1][b][hh2], h_reg[e]);
          if (lay == 2) stc(&g_enchid[t][b][hh2], valid ? h_reg[e] : 0.f);
        }
      }
    }
    gbar(w, ++bar);
  }

  if (j == 0){
    #pragma unroll
    for (int e = 0; e < 3; ++e){
      const int lay = (w < 255) ? lay0 : e;
      const int hh2 = (w < 255) ? (h0 + e) : 255;
      stc(&g_cfin[lay][b][hh2], c_reg[e]);
    }
  }
  gbar(w, ++bar);

  // ------- K/V projections (enchid: first-ever cached reads -> safe & fast) -------
  {
    const int b2 = w >> 2, t0 = (w & 3) * 64;
    const int n1 = tid & 127, rq = tid >> 7;
    for (int p = 0; p < 4; ++p){
      const int n = p*128 + n1;
      const float* wrow = (n < 256) ? (p_Wk + (size_t)n*HH) : (p_Wv + (size_t)(n-256)*HH);
      const float bias  = (n < 256) ? p_bk[n] : p_bv[n-256];
      const float4* wr4 = (const float4*)wrow;
      const float* hb = &g_enchid[t0 + rq*16][b2][0];
      const float4* hr[16];
      #pragma unroll
      for (int r = 0; r < 16; ++r) hr[r] = (const float4*)(hb + (size_t)r*NB*HH);
      float a16[16];
      #pragma unroll
      for (int r = 0; r < 16; ++r) a16[r] = 0.f;
      for (int k4 = 0; k4 < 64; ++k4){
        float4 wv = wr4[k4];
        #pragma unroll
        for (int r = 0; r < 16; ++r){ float4 h4 = hr[r][k4]; DOT4(a16[r], h4, wv); }
      }
      float* orow = (n < 256) ? &g_kp[b2][t0 + rq*16][n] : &g_vp[b2][t0 + rq*16][n-256];
      #pragma unroll
      for (int r = 0; r < 16; ++r) stc(orow + (size_t)r*HH, a16[r] + bias);
    }
  }

  // decoder weights for h=w (all 3 layers) -> LDS, K-permuted
  for (int fi = tid; fi < 3072; fi += 512){
    int g = fi / 768, k = fi % 768; int row = g*256 + w;
    float v = (k < 512) ? p_dWih0[(size_t)row*512 + k]
                        : p_dWhh[(size_t)row*HH + (k - 512)];
    int cb = k >> 8, kk = k & 255;
    s_w[(((cb*4 + g)*8 + ((kk & 15) >> 1))*36) + (((kk >> 4) << 1) | (kk & 1))] = v;
  }
  for (int fi = tid; fi < 2048; fi += 512){
    int g = fi / 512, k = fi % 512; int row = g*256 + w;
    float v = (k < 256) ? p_dWihR[(size_t)row*HH + k]
                        : p_dWhh[(size_t)(1024 + row)*HH + (k - 256)];
    int cb = k >> 8, kk = k & 255;
    s_w[3456 + (((cb*4 + g)*8 + ((kk & 15) >> 1))*36) + (((kk >> 4) << 1) | (kk & 1))] = v;
  }
  for (int fi = tid; fi < 2048; fi += 512){
    int g = fi / 512, k = fi % 512; int row = g*256 + w;
    float v = (k < 256) ? p_dWihR[(size_t)(1024 + row)*HH + k]
                        : p_dWhh[(size_t)(2048 + row)*HH + (k - 256)];
    int cb = k >> 8, kk = k & 255;
    s_w[5760 + (((cb*4 + g)*8 + ((kk & 15) >> 1))*36) + (((kk >> 4) << 1) | (kk & 1))] = v;
  }
  if (tid < 12){
    int l = tid >> 2, g = tid & 3; int row = g*256 + w;
    s_bdec[tid] = p_dbih[l*1024 + row] + p_dbhh[l*1024 + row];
  }
  gbar(w, ++bar);

  // ---------------- decoder init ----------------
  if (tid < 192){
    int fi = w*192 + tid;
    int l = fi >> 14, rem = fi & 16383;
    stc(&g_hdec[0][l][rem >> 8][rem & 255], ldc(&g_hring[l][1][rem >> 8][rem & 255]));
  }
  float c_d0 = 0.f, c_d1 = 0.f, c_d2 = 0.f;
  if (j == 0){
    c_d0 = ldc(&g_cfin[0][b][w]); c_d1 = ldc(&g_cfin[1][b][w]); c_d2 = ldc(&g_cfin[2][b][w]);
  }
  gbar(w, ++bar);

  // ---------------- decoder steps ----------------
  for (int st = 0; st < NSTEP; ++st){
    const int slot = st & 1, nxt = slot ^ 1;

    // ---- stage A: argmax-reduce, embed, attention, z0 (WGs 0..63) ----
    if (w < 64){
      const int bA = w;
      int tok = 0;                                  // SOS
      if (st > 0){
        float v = -1e38f; int idx = 0;
        if (tid < 256){ v = ldc(&g_wmax[tid][bA]); idx = ldi(&g_wmaxi[tid][bA]); }
        #pragma unroll
        for (int m = 1; m < 64; m <<= 1){
          float ov = __shfl_xor(v, m); int oi = __shfl_xor(idx, m);
          if (ov > v || (ov == v && oi < idx)){ v = ov; idx = oi; }
        }
        if ((tid & 63) == 0){ s_rv[tid >> 6] = v; s_ri[tid >> 6] = idx; }
        __syncthreads();
        if (tid == 0){
          float bv2 = s_rv[0]; int bi2 = s_ri[0];
          for (int q2 = 1; q2 < 8; ++q2){
            float ov = s_rv[q2]; int oi = s_ri[q2];
            if (ov > bv2 || (ov == bv2 && oi < bi2)){ bv2 = ov; bi2 = oi; }
          }
          s_ri[0] = bi2;
        }
        __syncthreads();
        tok = s_ri[0];
      }
      if (tid < 256)
        s_hs[tid] = ldc(&g_hdec[slot][0][bA][tid]) + ldc(&g_hdec[slot][1][bA][tid])
                  + ldc(&g_hdec[slot][2][bA][tid]);
      __syncthreads();
      if (tid < 256){                                // q = hsum @ Wq.T + bq
        float a = p_bq[tid];
        const float4* wr = (const float4*)(p_Wq + (size_t)tid*HH);
        #pragma unroll 8
        for (int k4 = 0; k4 < 64; ++k4){
          float4 wv = wr[k4]; float4 h4 = *(const float4*)&s_hs[k4*4]; DOT4(a, h4, wv);
        }
        s_q[tid] = a;
      }
      __syncthreads();
      if (tid < 256){                                // scores (kp cached, reused 25x)
        float a = 0.f;
        const float4* kr = (const float4*)&g_kp[bA][tid][0];
        #pragma unroll 8
        for (int k4 = 0; k4 < 64; ++k4){
          float4 kv = kr[k4]; float4 q4 = *(const float4*)&s_q[k4*4]; DOT4(a, q4, kv);
        }
        s_sc[tid] = a * 0.0625f;                     // 1/sqrt(256)
      }
      __syncthreads();
      {                                              // softmax
        float sv = (tid < 256) ? s_sc[tid] : -1e38f;
        float m2 = sv;
        #pragma unroll
        for (int m = 1; m < 64; m <<= 1) m2 = fmaxf(m2, __shfl_xor(m2, m));
        if ((tid & 63) == 0) s_rv[tid >> 6] = m2;
        __syncthreads();
        if (tid == 0){ float mm = s_rv[0]; for (int q2 = 1; q2 < 8; ++q2) mm = fmaxf(mm, s_rv[q2]); s_rv[0] = mm; }
        __syncthreads();
        const float mx = s_rv[0];
        float ev = (tid < 256) ? expf(sv - mx) : 0.f;
        float ss = ev;
        #pragma unroll
        for (int m = 1; m < 64; m <<= 1) ss += __shfl_xor(ss, m);
        __syncthreads();
        if ((tid & 63) == 0) s_rv[tid >> 6] = ss;
        __syncthreads();
        if (tid == 0){ float t2 = 0.f; for (int q2 = 0; q2 < 8; ++q2) t2 += s_rv[q2]; s_rv[0] = t2; }
        __syncthreads();
        if (tid < 256) s_at[tid] = ev / s_rv[0];
      }
      __syncthreads();
      if (tid < 256){                                // ctx = attn @ vp (cached)
        float a = 0.f;
        const float* vb = &g_vp[bA][0][tid];
        #pragma unroll 4
        for (int t4 = 0; t4 < 64; ++t4){
          float4 a4 = *(const float4*)&s_at[t4*4];
          a += a4.x*vb[(size_t)(t4*4+0)*HH] + a4.y*vb[(size_t)(t4*4+1)*HH]
             + a4.z*vb[(size_t)(t4*4+2)*HH] + a4.w*vb[(size_t)(t4*4+3)*HH];
        }
        s_ctx[tid] = a;
      }
      __syncthreads();
      if (tid < 256){                                // ctx @ Wo.T + bo ; z0
        float a = p_bo[tid];
        const float4* wr = (const float4*)(p_Wo + (size_t)tid*HH);
        #pragma unroll 8
        for (int k4 = 0; k4 < 64; ++k4){
          float4 wv = wr[k4]; float4 c4 = *(const float4*)&s_ctx[k4*4]; DOT4(a, c4, wv);
        }
        stc(&g_z0[bA][256 + tid], a);
        stc(&g_z0[bA][tid], p_demb[(size_t)tok*HH + tid]);
      }
    }
    gbar(w, ++bar);

    // ---- stages B/C/D: 3 LSTM layers, h=w per WG ----
    {
      float g4[4];
      dec_gates<3, 0>(s_w, &g_z0[b][0], &g_z0[b][256], &g_hdec[slot][0][b][0], j, g4);
      if (j == 0){
        float iv = g4[0]+s_bdec[0], fv = g4[1]+s_bdec[1], gv = g4[2]+s_bdec[2], ov = g4[3]+s_bdec[3];
        float c2 = sigf(fv)*c_d0 + sigf(iv)*tanhf(gv); c_d0 = c2;
        stc(&g_hdec[nxt][0][b][w], sigf(ov)*tanhf(c2));
      }
    }
    gbar(w, ++bar);
    {
      float g4[4];
      dec_gates<2, 3456>(s_w, &g_hdec[nxt][0][b][0], &g_hdec[slot][1][b][0], nullptr, j, g4);
      if (j == 0){
        float iv = g4[0]+s_bdec[4], fv = g4[1]+s_bdec[5], gv = g4[2]+s_bdec[6], ov = g4[3]+s_bdec[7];
        float c2 = sigf(fv)*c_d1 + sigf(iv)*tanhf(gv); c_d1 = c2;
        stc(&g_hdec[nxt][1][b][w], sigf(ov)*tanhf(c2));
      }
    }
    gbar(w, ++bar);
    {
      float g4[4];
      dec_gates<2, 5760>(s_w, &g_hdec[nxt][1][b][0], &g_hdec[slot][2][b][0], nullptr, j, g4);
      if (j == 0){
        float iv = g4[0]+s_bdec[8], fv = g4[1]+s_bdec[9], gv = g4[2]+s_bdec[10], ov = g4[3]+s_bdec[11];
        float c2 = sigf(fv)*c_d2 + sigf(iv)*tanhf(gv); c_d2 = c2;
        stc(&g_hdec[nxt][2][b][w], sigf(ov)*tanhf(c2));
      }
    }
    gbar(w, ++bar);

    // ---- stage E: logits GEMM (125 classes/WG) + partial argmax ----
    {
      // coalesced coherent staging of h2 (64x256) into LDS: lane-contiguous float2
      {
        const float* src = &g_hdec[nxt][2][0][0];
        #pragma unroll
        for (int u = 0; u < 16; ++u){
          int fo = 2*(tid + 512*u);
          float2 v = ld2(src + fo);
          *(float2*)(s_h2 + fo) = v;
        }
      }
      __syncthreads();

      const int cq = tid & 127, qb = tid >> 7;
      const bool cok = (cq < 125);
      const int c  = w*125 + cq;
      const int cc = cok ? c : (w*125);
      const float4* wr = (const float4*)(p_dW + (size_t)cc*HH);
      const float4* zr[16];
      #pragma unroll
      for (int r = 0; r < 16; ++r) zr[r] = (const float4*)&s_h2[(qb*16 + r)*HH];
      float a16[16];
      #pragma unroll
      for (int r = 0; r < 16; ++r) a16[r] = 0.f;
      for (int k4 = 0; k4 < 64; ++k4){
        float4 wv = wr[k4];
        #pragma unroll
        for (int r = 0; r < 16; ++r){ float4 z4 = zr[r][k4]; DOT4(a16[r], z4, wv); }
      }
      const float bias = cok ? p_db[cc] : 0.f;
      #pragma unroll
      for (int r = 0; r < 16; ++r){
        const int bb = qb*16 + r;
        float val = a16[r] + bias;
        if (cok) p_out[((size_t)bb*NSTEP + st)*NCLS + c] = val;
        float v = cok ? val : -1e38f;
        int idx = cok ? c : 0x7fffffff;
        #pragma unroll
        for (int m = 1; m < 64; m <<= 1){
          float ov = __shfl_xor(v, m); int oi = __shfl_xor(idx, m);
          if (ov > v || (ov == v && oi < idx)){ v = ov; idx = oi; }  // first-index tie-break
        }
        if ((tid & 63) == 0){ s_rv2[tid >> 6][r] = v; s_ri2[tid >> 6][r] = idx; }
      }
      __syncthreads();
      if (tid < 64){
        const int qb2 = tid >> 4, r = tid & 15;
        float v1 = s_rv2[qb2*2][r];   int i1 = s_ri2[qb2*2][r];
        float v2 = s_rv2[qb2*2+1][r]; int i2 = s_ri2[qb2*2+1][r];
        bool take2 = (v2 > v1) || (v2 == v1 && i2 < i1);
        stc(&g_wmax[w][qb2*16 + r],  take2 ? v2 : v1);
        sti(&g_wmaxi[w][qb2*16 + r], take2 ? i2 : i1);
      }
      __syncthreads();
    }
    gbar(w, ++bar);
  }
}

extern "C" void kernel_launch(void* const* d_in, const int* in_sizes, int n_in,
                              void* d_out, int out_size, void* d_ws, size_t ws_size,
                              hipStream_t stream){
  (void)in_sizes; (void)n_in; (void)out_size; (void)d_ws; (void)ws_size;
  const int*   x     = (const int*)d_in[0];
  const float* eemb  = (const float*)d_in[2];
  const float* eWih  = (const float*)d_in[3];
  const float* eWhh  = (const float*)d_in[4];
  const float* ebih  = (const float*)d_in[5];
  const float* ebhh  = (const float*)d_in[6];
  const float* Wq    = (const float*)d_in[7];
  const float* bq    = (const float*)d_in[8];
  const float* Wk    = (const float*)d_in[9];
  const float* bk    = (const float*)d_in[10];
  const float* Wv    = (const float*)d_in[11];
  const float* bv    = (const float*)d_in[12];
  const float* Wo    = (const float*)d_in[13];
  const float* bo    = (const float*)d_in[14];
  const float* demb  = (const float*)d_in[15];
  const float* dWih0 = (const float*)d_in[16];
  const float* dWihR = (const float*)d_in[17];
  const float* dWhh  = (const float*)d_in[18];
  const float* dbih  = (const float*)d_in[19];
  const float* dbhh  = (const float*)d_in[20];
  const float* dW    = (const float*)d_in[21];
  const float* db    = (const float*)d_in[22];
  float* out = (float*)d_out;

  k_zero_flags<<<dim3(1), dim3(256), 0, stream>>>();
  k_main<<<dim3(256), dim3(512), 0, stream>>>(
      x, eemb, eWih, eWhh, ebih, ebhh,
      Wq, bq, Wk, bk, Wv, bv, Wo, bo,
      demb, dWih0, dWihR, dWhh, dbih, dbhh, dW, db, out);
}

// Round 4
// 5993.518 us; speedup vs baseline: 4.3725x; 1.1497x over previous
//
#include <hip/hip_runtime.h>
#include <math.h>

// EncoderDecoderAttentionModel: B=64, T=256, H=D=256, L=3, NSTEPS=25, C=32000
#define TT    256
#define NB    64
#define HH    256
#define NSTEP 25
#define NCLS  32000
#define PADI  3

// ---------------- static device scratch ----------------
__device__ __align__(16) float g_hring[3][2][NB][HH];   // encoder h ping-pong (coherent)
__device__ __align__(16) float g_enchid[TT][NB][HH];    // write-once (sc1 store, cached read)
__device__ __align__(16) float g_kp[NB][TT][HH];        // write-once
__device__ __align__(16) float g_vp[NB][TT][HH];        // write-once
__device__ __align__(16) float g_cfin[3][NB][HH];       // write-once
__device__ __align__(16) float g_hdec[2][3][NB][HH];    // decoder h ping-pong (coherent)
__device__ __align__(16) float g_z0[NB][512];           // [embed ; ctx] (coherent)
__device__ float    g_wmax[256][NB];                    // argmax candidates (coherent)
__device__ int      g_wmaxi[256][NB];
__device__ int      g_len[NB];
__device__ unsigned g_arrive[256];                      // barrier arrive flags
__device__ unsigned g_release;                          // barrier release counter

__global__ void k_zero_flags(){
  g_arrive[threadIdx.x] = 0u;
  if (threadIdx.x == 0) g_release = 0u;
}

__device__ __forceinline__ float sigf(float v){ return 1.0f / (1.0f + expf(-v)); }

// ---- coherent accessors (agent scope, relaxed): visible chip-wide w/o fences ----
#define SCOPE_AG __HIP_MEMORY_SCOPE_AGENT
typedef unsigned long long u64;
__device__ __forceinline__ float2 ld2(const float* p){
  u64 v = __hip_atomic_load((const u64*)p, __ATOMIC_RELAXED, SCOPE_AG);
  float2 r; __builtin_memcpy(&r, &v, 8); return r;
}
__device__ __forceinline__ void st2(float* p, float2 f){
  u64 v; __builtin_memcpy(&v, &f, 8);
  __hip_atomic_store((u64*)p, v, __ATOMIC_RELAXED, SCOPE_AG);
}
__device__ __forceinline__ float ldc(const float* p){ return __hip_atomic_load(p, __ATOMIC_RELAXED, SCOPE_AG); }
__device__ __forceinline__ void  stc(float* p, float v){ __hip_atomic_store(p, v, __ATOMIC_RELAXED, SCOPE_AG); }
__device__ __forceinline__ int   ldi(const int* p){ return __hip_atomic_load(p, __ATOMIC_RELAXED, SCOPE_AG); }
__device__ __forceinline__ void  sti(int* p, int v){ __hip_atomic_store(p, v, __ATOMIC_RELAXED, SCOPE_AG); }
__device__ __forceinline__ unsigned ldu(const unsigned* p){ return __hip_atomic_load(p, __ATOMIC_RELAXED, SCOPE_AG); }
__device__ __forceinline__ void  stu(unsigned* p, unsigned v){ __hip_atomic_store(p, v, __ATOMIC_RELAXED, SCOPE_AG); }

#define DOT4(a_, x_, w_) (a_) += (x_).x*(w_).x + (x_).y*(w_).y + (x_).z*(w_).z + (x_).w*(w_).w

// LDS weight layout: [cb][gate][j][36] with K-permutation k = 16u + 2j + c
#define WENC(cb,g,jj,u) (((((cb)*12+(g))*8+(jj))*36)+(u))

// ---- two-level master-gather grid barrier ----
// Arrive: 256 distinct-address stores (parallel). Gather: only WG 0 polls the
// 256 arrive flags. Release: single monotonic counter, polled by 1 lane/WG.
// vmcnt(0) before the arrive store orders data-at-LLC before flag visibility.
__device__ __forceinline__ void gbar(int w, unsigned target){
  asm volatile("s_waitcnt vmcnt(0)" ::: "memory");
  __syncthreads();
  if (threadIdx.x == 0) stu(&g_arrive[w], target);
  if (w == 0){
    if (threadIdx.x < 64){
      const int i4 = threadIdx.x * 4;
      for (;;){
        unsigned a0 = ldu(&g_arrive[i4+0]);
        unsigned a1 = ldu(&g_arrive[i4+1]);
        unsigned a2 = ldu(&g_arrive[i4+2]);
        unsigned a3 = ldu(&g_arrive[i4+3]);
        if (__all((a0>=target) && (a1>=target) && (a2>=target) && (a3>=target))) break;
        __builtin_amdgcn_s_sleep(1);
      }
      if (threadIdx.x == 0) stu(&g_release, target);
    }
  } else {
    if (threadIdx.x == 0){
      while (ldu(&g_release) < target) __builtin_amdgcn_s_sleep(2);
    }
  }
  __syncthreads();
}

// decoder LSTM gate GEMM: 4 gate rows (h index = WG id), inputs coherent+coalesced.
template<int NCB, int BASE>
__device__ __forceinline__ void dec_gates(const float* sw, const float* i0, const float* i1,
                                          const float* i2, int j, float out4[4]){
  float a0=0.f, a1=0.f, a2=0.f, a3=0.f;
  const float* ips[3] = { i0, i1, i2 };
  #pragma unroll
  for (int cb = 0; cb < NCB; ++cb){
    float2 xin[16];
    #pragma unroll
    for (int u = 0; u < 16; ++u) xin[u] = ld2(ips[cb] + u*16 + 2*j);
    #pragma unroll
    for (int u2 = 0; u2 < 8; ++u2){
      float2 pa = xin[2*u2], pb = xin[2*u2+1];
      const float* wb = &sw[BASE + (((cb*4+0)*8+j)*36) + u2*4];
      float4 w0 = *(const float4*)(wb);
      float4 w1 = *(const float4*)(wb + 288);
      float4 w2 = *(const float4*)(wb + 576);
      float4 w3 = *(const float4*)(wb + 864);
      a0 += pa.x*w0.x + pa.y*w0.y + pb.x*w0.z + pb.y*w0.w;
      a1 += pa.x*w1.x + pa.y*w1.y + pb.x*w1.z + pb.y*w1.w;
      a2 += pa.x*w2.x + pa.y*w2.y + pb.x*w2.z + pb.y*w2.w;
      a3 += pa.x*w3.x + pa.y*w3.y + pb.x*w3.z + pb.y*w3.w;
    }
  }
  #pragma unroll
  for (int m = 1; m < 8; m <<= 1){
    a0 += __shfl_xor(a0, m); a1 += __shfl_xor(a1, m);
    a2 += __shfl_xor(a2, m); a3 += __shfl_xor(a3, m);
  }
  out4[0]=a0; out4[1]=a1; out4[2]=a2; out4[3]=a3;
}

__global__ void __launch_bounds__(512, 1)
k_main(const int*   __restrict__ p_x,
       const float* __restrict__ p_eemb,
       const float* __restrict__ p_eWih,  const float* __restrict__ p_eWhh,
       const float* __restrict__ p_ebih,  const float* __restrict__ p_ebhh,
       const float* __restrict__ p_Wq, const float* __restrict__ p_bq,
       const float* __restrict__ p_Wk, const float* __restrict__ p_bk,
       const float* __restrict__ p_Wv, const float* __restrict__ p_bv,
       const float* __restrict__ p_Wo, const float* __restrict__ p_bo,
       const float* __restrict__ p_demb,
       const float* __restrict__ p_dWih0, const float* __restrict__ p_dWihR,
       const float* __restrict__ p_dWhh,
       const float* __restrict__ p_dbih,  const float* __restrict__ p_dbhh,
       const float* __restrict__ p_dW,    const float* __restrict__ p_db,
       float* __restrict__ p_out)
{
  __shared__ __align__(16) float s_w[8064];       // enc: 6912 used; dec: 8064 used
  __shared__ __align__(16) float s_h2[NB*HH];     // stage-E h2 staging, flat [64][256]
  __shared__ float s_benc[12];
  __shared__ float s_bdec[12];
  __shared__ __align__(16) float s_hs[256];
  __shared__ __align__(16) float s_q[256];
  __shared__ __align__(16) float s_sc[256];
  __shared__ __align__(16) float s_at[256];
  __shared__ __align__(16) float s_ctx[256];
  __shared__ float s_rv[8];  __shared__ int s_ri[8];
  __shared__ float s_rv2[8][16]; __shared__ int s_ri2[8][16];

  const int w   = blockIdx.x;
  const int tid = threadIdx.x;
  const int b   = tid >> 3;      // batch lane (0..63)
  const int j   = tid & 7;       // K-split lane (0..7); owns k = {16u + 2j + c}
  unsigned bar  = 0;

  const int lay0 = (w < 255) ? (w / 85) : 0;
  const int h0   = (w < 255) ? ((w - lay0*85) * 3) : 0;

  // ---------------- init: lengths, encoder weights -> LDS (permuted), zero ring ----
  for (int fi = tid; fi < 6144; fi += 512){
    int g = fi >> 9, k = fi & 511;
    int e = g >> 2, gt = g & 3;
    int l   = (w < 255) ? lay0 : e;
    int hh2 = (w < 255) ? (h0 + e) : 255;
    int row = gt*256 + hh2;
    float v = (k < 256) ? p_eWih[((size_t)l*1024 + row)*256 + k]
                        : p_eWhh[((size_t)l*1024 + row)*256 + (k - 256)];
    int cb = k >> 8, kk = k & 255;
    s_w[WENC(cb, g, (kk & 15) >> 1, ((kk >> 4) << 1) | (kk & 1))] = v;
  }
  if (tid < 12){
    int e = tid >> 2, gt = tid & 3;
    int l   = (w < 255) ? lay0 : e;
    int hh2 = (w < 255) ? (h0 + e) : 255;
    int row = gt*256 + hh2;
    s_benc[tid] = p_ebih[l*1024 + row] + p_ebhh[l*1024 + row];
  }
  if (w < 64){
    int cnt = 0;
    if (tid < 256) cnt = (p_x[w*TT + tid] != PADI) ? 1 : 0;
    #pragma unroll
    for (int m = 1; m < 64; m <<= 1) cnt += __shfl_xor(cnt, m);
    if ((tid & 63) == 0) s_ri[tid >> 6] = cnt;
    __syncthreads();
    if (tid == 0){ int t2 = 0; for (int q2 = 0; q2 < 8; ++q2) t2 += s_ri[q2]; sti(&g_len[w], t2); }
  }
  if (tid < 192){                       // zero initial-state slot (slot 1 == "t=-1")
    int fi = w*192 + tid;
    int l = fi >> 14, rem = fi & 16383;
    stc(&g_hring[l][1][rem >> 8][rem & 255], 0.f);
  }
  gbar(w, ++bar);

  const int len_b = ldi(&g_len[b]);

  // ---------------- encoder: layer-wavefront over diagonals ----------------
  float c_reg[3] = {0.f,0.f,0.f};
  float h_reg[3] = {0.f,0.f,0.f};

  for (int sdiag = 0; sdiag < TT + 2; ++sdiag){
    float acc[12];
    #pragma unroll
    for (int g = 0; g < 12; ++g) acc[g] = 0.f;

    if (w < 255){
      const int t = sdiag - lay0;
      if (t >= 0 && t < TT){
        float2 x2[16], h2[16];
        if (lay0 == 0){
          const float* xs = p_eemb + (size_t)p_x[b*TT + t]*HH;
          #pragma unroll
          for (int u = 0; u < 16; ++u) x2[u] = *(const float2*)(xs + u*16 + 2*j);
        } else {
          const float* xs = &g_hring[lay0-1][t & 1][b][0];
          #pragma unroll
          for (int u = 0; u < 16; ++u) x2[u] = ld2(xs + u*16 + 2*j);
        }
        {
          const float* hsv = &g_hring[lay0][(t & 1) ^ 1][b][0];
          #pragma unroll
          for (int u = 0; u < 16; ++u) h2[u] = ld2(hsv + u*16 + 2*j);
        }
        #pragma unroll
        for (int u2 = 0; u2 < 8; ++u2){
          float2 xa = x2[2*u2], xb = x2[2*u2+1];
          float2 ha = h2[2*u2], hb = h2[2*u2+1];
          #pragma unroll
          for (int g = 0; g < 12; ++g){
            float4 wx = *(const float4*)&s_w[WENC(0, g, j, u2*4)];
            float4 wh = *(const float4*)&s_w[WENC(1, g, j, u2*4)];
            acc[g] += xa.x*wx.x + xa.y*wx.y + xb.x*wx.z + xb.y*wx.w
                    + ha.x*wh.x + ha.y*wh.y + hb.x*wh.z + hb.y*wh.w;
          }
        }
      }
    } else {
      #pragma unroll
      for (int e = 0; e < 3; ++e){
        const int t = sdiag - e;
        if (t >= 0 && t < TT){
          float2 x2[16], h2[16];
          if (e == 0){
            const float* xs = p_eemb + (size_t)p_x[b*TT + t]*HH;
            #pragma unroll
            for (int u = 0; u < 16; ++u) x2[u] = *(const float2*)(xs + u*16 + 2*j);
          } else {
            const float* xs = &g_hring[e-1][t & 1][b][0];
            #pragma unroll
            for (int u = 0; u < 16; ++u) x2[u] = ld2(xs + u*16 + 2*j);
          }
          {
            const float* hsv = &g_hring[e][(t & 1) ^ 1][b][0];
            #pragma unroll
            for (int u = 0; u < 16; ++u) h2[u] = ld2(hsv + u*16 + 2*j);
          }
          #pragma unroll
          for (int u2 = 0; u2 < 8; ++u2){
            float2 xa = x2[2*u2], xb = x2[2*u2+1];
            float2 ha = h2[2*u2], hb = h2[2*u2+1];
            #pragma unroll
            for (int g2 = 0; g2 < 4; ++g2){
              float4 wx = *(const float4*)&s_w[WENC(0, e*4+g2, j, u2*4)];
              float4 wh = *(const float4*)&s_w[WENC(1, e*4+g2, j, u2*4)];
              acc[e*4+g2] += xa.x*wx.x + xa.y*wx.y + xb.x*wx.z + xb.y*wx.w
                           + ha.x*wh.x + ha.y*wh.y + hb.x*wh.z + hb.y*wh.w;
            }
          }
        }
      }
    }

    #pragma unroll
    for (int g = 0; g < 12; ++g){
      float v = acc[g];
      v += __shfl_xor(v, 1); v += __shfl_xor(v, 2); v += __shfl_xor(v, 4);
      acc[g] = v;
    }

    if (j == 0){
      #pragma unroll
      for (int e = 0; e < 3; ++e){
        const int lay = (w < 255) ? lay0 : e;
        const int hh2 = (w < 255) ? (h0 + e) : 255;
        const int t = sdiag - lay;
        if (t >= 0 && t < TT){
          float iv = acc[e*4+0] + s_benc[e*4+0];
          float fv = acc[e*4+1] + s_benc[e*4+1];
          float gv = acc[e*4+2] + s_benc[e*4+2];
          float ov = acc[e*4+3] + s_benc[e*4+3];
          float c2 = sigf(fv)*c_reg[e] + sigf(iv)*tanhf(gv);
          float h2v = sigf(ov)*tanhf(c2);
          bool valid = (t < len_b);
          if (valid){ c_reg[e] = c2; h_reg[e] = h2v; }   // freeze past length
          stc(&g_hring[lay][t & 1][b][hh2], h_reg[e]);
          if (lay == 2) stc(&g_enchid[t][b][hh2], valid ? h_reg[e] : 0.f);
        }
      }
    }
    gbar(w, ++bar);
  }

  if (j == 0){
    #pragma unroll
    for (int e = 0; e < 3; ++e){
      const int lay = (w < 255) ? lay0 : e;
      const int hh2 = (w < 255) ? (h0 + e) : 255;
      stc(&g_cfin[lay][b][hh2], c_reg[e]);
    }
  }
  gbar(w, ++bar);

  // ------- K/V projections (enchid coherent-written, read via ldc-free cached path) -------
  {
    const int b2 = w >> 2, t0 = (w & 3) * 64;
    const int n1 = tid & 127, rq = tid >> 7;
    for (int p = 0; p < 4; ++p){
      const int n = p*128 + n1;
      const float* wrow = (n < 256) ? (p_Wk + (size_t)n*HH) : (p_Wv + (size_t)(n-256)*HH);
      const float bias  = (n < 256) ? p_bk[n] : p_bv[n-256];
      const float4* wr4 = (const float4*)wrow;
      const float* hb = &g_enchid[t0 + rq*16][b2][0];
      const float4* hr[16];
      #pragma unroll
      for (int r = 0; r < 16; ++r) hr[r] = (const float4*)(hb + (size_t)r*NB*HH);
      float a16[16];
      #pragma unroll
      for (int r = 0; r < 16; ++r) a16[r] = 0.f;
      for (int k4 = 0; k4 < 64; ++k4){
        float4 wv = wr4[k4];
        #pragma unroll
        for (int r = 0; r < 16; ++r){ float4 h4 = hr[r][k4]; DOT4(a16[r], h4, wv); }
      }
      float* orow = (n < 256) ? &g_kp[b2][t0 + rq*16][n] : &g_vp[b2][t0 + rq*16][n-256];
      #pragma unroll
      for (int r = 0; r < 16; ++r) stc(orow + (size_t)r*HH, a16[r] + bias);
    }
  }

  // decoder weights for h=w (all 3 layers) -> LDS, K-permuted
  for (int fi = tid; fi < 3072; fi += 512){
    int g = fi / 768, k = fi % 768; int row = g*256 + w;
    float v = (k < 512) ? p_dWih0[(size_t)row*512 + k]
                        : p_dWhh[(size_t)row*HH + (k - 512)];
    int cb = k >> 8, kk = k & 255;
    s_w[(((cb*4 + g)*8 + ((kk & 15) >> 1))*36) + (((kk >> 4) << 1) | (kk & 1))] = v;
  }
  for (int fi = tid; fi < 2048; fi += 512){
    int g = fi / 512, k = fi % 512; int row = g*256 + w;
    float v = (k < 256) ? p_dWihR[(size_t)row*HH + k]
                        : p_dWhh[(size_t)(1024 + row)*HH + (k - 256)];
    int cb = k >> 8, kk = k & 255;
    s_w[3456 + (((cb*4 + g)*8 + ((kk & 15) >> 1))*36) + (((kk >> 4) << 1) | (kk & 1))] = v;
  }
  for (int fi = tid; fi < 2048; fi += 512){
    int g = fi / 512, k = fi % 512; int row = g*256 + w;
    float v = (k < 256) ? p_dWihR[(size_t)(1024 + row)*HH + k]
                        : p_dWhh[(size_t)(2048 + row)*HH + (k - 256)];
    int cb = k >> 8, kk = k & 255;
    s_w[5760 + (((cb*4 + g)*8 + ((kk & 15) >> 1))*36) + (((kk >> 4) << 1) | (kk & 1))] = v;
  }
  if (tid < 12){
    int l = tid >> 2, g = tid & 3; int row = g*256 + w;
    s_bdec[tid] = p_dbih[l*1024 + row] + p_dbhh[l*1024 + row];
  }
  gbar(w, ++bar);

  // ---------------- decoder init ----------------
  if (tid < 192){
    int fi = w*192 + tid;
    int l = fi >> 14, rem = fi & 16383;
    stc(&g_hdec[0][l][rem >> 8][rem & 255], ldc(&g_hring[l][1][rem >> 8][rem & 255]));
  }
  float c_d0 = 0.f, c_d1 = 0.f, c_d2 = 0.f;
  if (j == 0){
    c_d0 = ldc(&g_cfin[0][b][w]); c_d1 = ldc(&g_cfin[1][b][w]); c_d2 = ldc(&g_cfin[2][b][w]);
  }
  gbar(w, ++bar);

  // ---------------- decoder steps ----------------
  for (int st = 0; st < NSTEP; ++st){
    const int slot = st & 1, nxt = slot ^ 1;

    // ---- stage A: argmax-reduce, embed, attention, z0 (WGs 0..63) ----
    if (w < 64){
      const int bA = w;
      int tok = 0;                                  // SOS
      if (st > 0){
        float v = -1e38f; int idx = 0;
        if (tid < 256){ v = ldc(&g_wmax[tid][bA]); idx = ldi(&g_wmaxi[tid][bA]); }
        #pragma unroll
        for (int m = 1; m < 64; m <<= 1){
          float ov = __shfl_xor(v, m); int oi = __shfl_xor(idx, m);
          if (ov > v || (ov == v && oi < idx)){ v = ov; idx = oi; }
        }
        if ((tid & 63) == 0){ s_rv[tid >> 6] = v; s_ri[tid >> 6] = idx; }
        __syncthreads();
        if (tid == 0){
          float bv2 = s_rv[0]; int bi2 = s_ri[0];
          for (int q2 = 1; q2 < 8; ++q2){
            float ov = s_rv[q2]; int oi = s_ri[q2];
            if (ov > bv2 || (ov == bv2 && oi < bi2)){ bv2 = ov; bi2 = oi; }
          }
          s_ri[0] = bi2;
        }
        __syncthreads();
        tok = s_ri[0];
      }
      if (tid < 256)
        s_hs[tid] = ldc(&g_hdec[slot][0][bA][tid]) + ldc(&g_hdec[slot][1][bA][tid])
                  + ldc(&g_hdec[slot][2][bA][tid]);
      __syncthreads();
      if (tid < 256){                                // q = hsum @ Wq.T + bq
        float a = p_bq[tid];
        const float4* wr = (const float4*)(p_Wq + (size_t)tid*HH);
        #pragma unroll 8
        for (int k4 = 0; k4 < 64; ++k4){
          float4 wv = wr[k4]; float4 h4 = *(const float4*)&s_hs[k4*4]; DOT4(a, h4, wv);
        }
        s_q[tid] = a;
      }
      __syncthreads();
      if (tid < 256){                                // scores (kp cached, reused 25x)
        float a = 0.f;
        const float4* kr = (const float4*)&g_kp[bA][tid][0];
        #pragma unroll 8
        for (int k4 = 0; k4 < 64; ++k4){
          float4 kv = kr[k4]; float4 q4 = *(const float4*)&s_q[k4*4]; DOT4(a, q4, kv);
        }
        s_sc[tid] = a * 0.0625f;                     // 1/sqrt(256)
      }
      __syncthreads();
      {                                              // softmax
        float sv = (tid < 256) ? s_sc[tid] : -1e38f;
        float m2 = sv;
        #pragma unroll
        for (int m = 1; m < 64; m <<= 1) m2 = fmaxf(m2, __shfl_xor(m2, m));
        if ((tid & 63) == 0) s_rv[tid >> 6] = m2;
        __syncthreads();
        if (tid == 0){ float mm = s_rv[0]; for (int q2 = 1; q2 < 8; ++q2) mm = fmaxf(mm, s_rv[q2]); s_rv[0] = mm; }
        __syncthreads();
        const float mx = s_rv[0];
        float ev = (tid < 256) ? expf(sv - mx) : 0.f;
        float ss = ev;
        #pragma unroll
        for (int m = 1; m < 64; m <<= 1) ss += __shfl_xor(ss, m);
        __syncthreads();
        if ((tid & 63) == 0) s_rv[tid >> 6] = ss;
        __syncthreads();
        if (tid == 0){ float t2 = 0.f; for (int q2 = 0; q2 < 8; ++q2) t2 += s_rv[q2]; s_rv[0] = t2; }
        __syncthreads();
        if (tid < 256) s_at[tid] = ev / s_rv[0];
      }
      __syncthreads();
      if (tid < 256){                                // ctx = attn @ vp (cached)
        float a = 0.f;
        const float* vb = &g_vp[bA][0][tid];
        #pragma unroll 4
        for (int t4 = 0; t4 < 64; ++t4){
          float4 a4 = *(const float4*)&s_at[t4*4];
          a += a4.x*vb[(size_t)(t4*4+0)*HH] + a4.y*vb[(size_t)(t4*4+1)*HH]
             + a4.z*vb[(size_t)(t4*4+2)*HH] + a4.w*vb[(size_t)(t4*4+3)*HH];
        }
        s_ctx[tid] = a;
      }
      __syncthreads();
      if (tid < 256){                                // ctx @ Wo.T + bo ; z0
        float a = p_bo[tid];
        const float4* wr = (const float4*)(p_Wo + (size_t)tid*HH);
        #pragma unroll 8
        for (int k4 = 0; k4 < 64; ++k4){
          float4 wv = wr[k4]; float4 c4 = *(const float4*)&s_ctx[k4*4]; DOT4(a, c4, wv);
        }
        stc(&g_z0[bA][256 + tid], a);
        stc(&g_z0[bA][tid], p_demb[(size_t)tok*HH + tid]);
      }
    }
    gbar(w, ++bar);

    // ---- stages B/C/D: 3 LSTM layers, h=w per WG ----
    {
      float g4[4];
      dec_gates<3, 0>(s_w, &g_z0[b][0], &g_z0[b][256], &g_hdec[slot][0][b][0], j, g4);
      if (j == 0){
        float iv = g4[0]+s_bdec[0], fv = g4[1]+s_bdec[1], gv = g4[2]+s_bdec[2], ov = g4[3]+s_bdec[3];
        float c2 = sigf(fv)*c_d0 + sigf(iv)*tanhf(gv); c_d0 = c2;
        stc(&g_hdec[nxt][0][b][w], sigf(ov)*tanhf(c2));
      }
    }
    gbar(w, ++bar);
    {
      float g4[4];
      dec_gates<2, 3456>(s_w, &g_hdec[nxt][0][b][0], &g_hdec[slot][1][b][0], nullptr, j, g4);
      if (j == 0){
        float iv = g4[0]+s_bdec[4], fv = g4[1]+s_bdec[5], gv = g4[2]+s_bdec[6], ov = g4[3]+s_bdec[7];
        float c2 = sigf(fv)*c_d1 + sigf(iv)*tanhf(gv); c_d1 = c2;
        stc(&g_hdec[nxt][1][b][w], sigf(ov)*tanhf(c2));
      }
    }
    gbar(w, ++bar);
    {
      float g4[4];
      dec_gates<2, 5760>(s_w, &g_hdec[nxt][1][b][0], &g_hdec[slot][2][b][0], nullptr, j, g4);
      if (j == 0){
        float iv = g4[0]+s_bdec[8], fv = g4[1]+s_bdec[9], gv = g4[2]+s_bdec[10], ov = g4[3]+s_bdec[11];
        float c2 = sigf(fv)*c_d2 + sigf(iv)*tanhf(gv); c_d2 = c2;
        stc(&g_hdec[nxt][2][b][w], sigf(ov)*tanhf(c2));
      }
    }
    gbar(w, ++bar);

    // ---- stage E: logits GEMM (125 classes/WG) + partial argmax ----
    {
      // coalesced coherent staging of h2 (64x256) into LDS: lane-contiguous float2
      {
        const float* src = &g_hdec[nxt][2][0][0];
        #pragma unroll
        for (int u = 0; u < 16; ++u){
          int fo = 2*(tid + 512*u);
          float2 v = ld2(src + fo);
          *(float2*)(s_h2 + fo) = v;
        }
      }
      __syncthreads();

      const int cq = tid & 127, qb = tid >> 7;
      const bool cok = (cq < 125);
      const int c  = w*125 + cq;
      const int cc = cok ? c : (w*125);
      const float4* wr = (const float4*)(p_dW + (size_t)cc*HH);
      const float4* zr[16];
      #pragma unroll
      for (int r = 0; r < 16; ++r) zr[r] = (const float4*)&s_h2[(qb*16 + r)*HH];
      float a16[16];
      #pragma unroll
      for (int r = 0; r < 16; ++r) a16[r] = 0.f;
      for (int k4 = 0; k4 < 64; ++k4){
        float4 wv = wr[k4];
        #pragma unroll
        for (int r = 0; r < 16; ++r){ float4 z4 = zr[r][k4]; DOT4(a16[r], z4, wv); }
      }
      const float bias = cok ? p_db[cc] : 0.f;
      #pragma unroll
      for (int r = 0; r < 16; ++r){
        const int bb = qb*16 + r;
        float val = a16[r] + bias;
        if (cok) p_out[((size_t)bb*NSTEP + st)*NCLS + c] = val;
        float v = cok ? val : -1e38f;
        int idx = cok ? c : 0x7fffffff;
        #pragma unroll
        for (int m = 1; m < 64; m <<= 1){
          float ov = __shfl_xor(v, m); int oi = __shfl_xor(idx, m);
          if (ov > v || (ov == v && oi < idx)){ v = ov; idx = oi; }  // first-index tie-break
        }
        if ((tid & 63) == 0){ s_rv2[tid >> 6][r] = v; s_ri2[tid >> 6][r] = idx; }
      }
      __syncthreads();
      if (tid < 64){
        const int qb2 = tid >> 4, r = tid & 15;
        float v1 = s_rv2[qb2*2][r];   int i1 = s_ri2[qb2*2][r];
        float v2 = s_rv2[qb2*2+1][r]; int i2 = s_ri2[qb2*2+1][r];
        bool take2 = (v2 > v1) || (v2 == v1 && i2 < i1);
        stc(&g_wmax[w][qb2*16 + r],  take2 ? v2 : v1);
        sti(&g_wmaxi[w][qb2*16 + r], take2 ? i2 : i1);
      }
      __syncthreads();
    }
    gbar(w, ++bar);
  }
}

extern "C" void kernel_launch(void* const* d_in, const int* in_sizes, int n_in,
                              void* d_out, int out_size, void* d_ws, size_t ws_size,
                              hipStream_t stream){
  (void)in_sizes; (void)n_in; (void)out_size; (void)d_ws; (void)ws_size;
  const int*   x     = (const int*)d_in[0];
  const float* eemb  = (const float*)d_in[2];
  const float* eWih  = (const float*)d_in[3];
  const float* eWhh  = (const float*)d_in[4];
  const float* ebih  = (const float*)d_in[5];
  const float* ebhh  = (const float*)d_in[6];
  const float* Wq    = (const float*)d_in[7];
  const float* bq    = (const float*)d_in[8];
  const float* Wk    = (const float*)d_in[9];
  const float* bk    = (const float*)d_in[10];
  const float* Wv    = (const float*)d_in[11];
  const float* bv    = (const float*)d_in[12];
  const float* Wo    = (const float*)d_in[13];
  const float* bo    = (const float*)d_in[14];
  const float* demb  = (const float*)d_in[15];
  const float* dWih0 = (const float*)d_in[16];
  const float* dWihR = (const float*)d_in[17];
  const float* dWhh  = (const float*)d_in[18];
  const float* dbih  = (const float*)d_in[19];
  const float* dbhh  = (const float*)d_in[20];
  const float* dW    = (const float*)d_in[21];
  const float* db    = (const float*)d_in[22];
  float* out = (float*)d_out;

  k_zero_flags<<<dim3(1), dim3(256), 0, stream>>>();
  k_main<<<dim3(256), dim3(512), 0, stream>>>(
      x, eemb, eWih, eWhh, ebih, ebhh,
      Wq, bq, Wk, bk, Wv, bv, Wo, bo,
      demb, dWih0, dWihR, dWhh, dbih, dbhh, dW, db, out);
}